// Round 11
// baseline (160.902 us; speedup 1.0000x reference)
//
#include <hip/hip_runtime.h>

typedef __bf16 bf16x8 __attribute__((ext_vector_type(8)));
typedef float f32x4 __attribute__((ext_vector_type(4)));
typedef float f32x16 __attribute__((ext_vector_type(16)));

__device__ __forceinline__ void gload16(const void* g, void* l) {
    __builtin_amdgcn_global_load_lds(
        (const __attribute__((address_space(1))) unsigned int*)g,
        (__attribute__((address_space(3))) unsigned int*)l, 16, 0, 0);
}

// ---- fused pre-pass: x fp32->bf16 (blocks [0,nxb)), W dequant (blocks [nxb,...)) ----
__global__ void k_prep(const float* __restrict__ x, __bf16* __restrict__ xb, size_t nx,
                       const int* __restrict__ wq, const float* __restrict__ scale,
                       const float* __restrict__ zp, __bf16* __restrict__ wb,
                       int K, int GS, int NG, int nxb) {
    const int bid = (int)blockIdx.x;
    if (bid < nxb) {
        size_t i = ((size_t)bid * blockDim.x + threadIdx.x) * 8;
        if (i >= nx) return;
        const float4 a = *(const float4*)(x + i);
        const float4 b = *(const float4*)(x + i + 4);
        bf16x8 v;
        v[0] = (__bf16)a.x; v[1] = (__bf16)a.y; v[2] = (__bf16)a.z; v[3] = (__bf16)a.w;
        v[4] = (__bf16)b.x; v[5] = (__bf16)b.y; v[6] = (__bf16)b.z; v[7] = (__bf16)b.w;
        *(bf16x8*)(xb + i) = v;
    } else {
        size_t i = ((size_t)(bid - nxb) * blockDim.x + threadIdx.x) * 8;
        int o = (int)(i / K);
        int k = (int)(i % K);
        int g = k / GS;
        float s = scale[(size_t)o * NG + g];
        float z = zp[(size_t)o * NG + g];
        const int4 q0 = *(const int4*)(wq + i);
        const int4 q1 = *(const int4*)(wq + i + 4);
        bf16x8 v;
        v[0] = (__bf16)(((float)q0.x - z) * s); v[1] = (__bf16)(((float)q0.y - z) * s);
        v[2] = (__bf16)(((float)q0.z - z) * s); v[3] = (__bf16)(((float)q0.w - z) * s);
        v[4] = (__bf16)(((float)q1.x - z) * s); v[5] = (__bf16)(((float)q1.y - z) * s);
        v[6] = (__bf16)(((float)q1.z - z) * s); v[7] = (__bf16)(((float)q1.w - z) * s);
        *(bf16x8*)(wb + i) = v;
    }
}

// ---- standalone dequant (fallback MODE 1 path) ----
__global__ void k_dequant_w(const int* __restrict__ wq, const float* __restrict__ scale,
                            const float* __restrict__ zp, __bf16* __restrict__ wb,
                            int K, int GS, int NG) {
    size_t i = ((size_t)blockIdx.x * blockDim.x + threadIdx.x) * 8;
    int o = (int)(i / K);
    int k = (int)(i % K);
    int g = k / GS;
    float s = scale[(size_t)o * NG + g];
    float z = zp[(size_t)o * NG + g];
    const int4 q0 = *(const int4*)(wq + i);
    const int4 q1 = *(const int4*)(wq + i + 4);
    bf16x8 v;
    v[0] = (__bf16)(((float)q0.x - z) * s); v[1] = (__bf16)(((float)q0.y - z) * s);
    v[2] = (__bf16)(((float)q0.z - z) * s); v[3] = (__bf16)(((float)q0.w - z) * s);
    v[4] = (__bf16)(((float)q1.x - z) * s); v[5] = (__bf16)(((float)q1.y - z) * s);
    v[6] = (__bf16)(((float)q1.z - z) * s); v[7] = (__bf16)(((float)q1.w - z) * s);
    *(bf16x8*)(wb + i) = v;
}

// =====================================================================
// 256x256 deep-pipelined GEMM, BK=32, 4 LDS buffers, ONE barrier/tile.
// ROUND-5 SKELETON (verified: conflicts 0, 125us @ 16x16 shape) with
// MFMA shape switched to 32x32x16 (2382 vs 2075 TF pipe, half the
// instruction count). Per wave: 4 mt (32 rows) x 2 nt (32 cols) tiles,
// acc = f32x16[4][2] (128 VGPR, unchanged budget).
// Phase structure (symmetric, no B ping-pong):
//   ph0: STAGE_A(t+3); read a1/bb1 (kh=1) of t [6]; lgkm(6) ->
//        8 MFMA kh=0 (uses a0/bb0 read last phase)
//   ph1: STAGE_B(t+3); read a0/bb0 of t+1 [6]; lgkm(6) ->
//        8 MFMA kh=1 (uses a1/bb1)
// lgkm ledger: 6 outstanding at each phase top; lgkm(6) drains exactly
// the previous phase's 6 reads (the cluster's operands). vmcnt(4) at
// tile top: identical ledger to round 5.
// A/B fragment load: lane reads row (lane&31), 8 contiguous k at chunk
// (kh*2 + (lane>>5)); same bijection for A and B => k-order-independent
// correctness. C/D layout (HW-measured m74/m101): col=lane&31,
// row=(reg&3)+8*(reg>>2)+4*(lane>>5).
// Swizzle (T2): LDS[row][j]=G[row][j^((row>>1)&3)]; read chunk XORs
// ((l31>>1)&3). Slot check per 8-lane group: all 8 distinct slots.
// =====================================================================
#define BKg 32
#define TILEB 32768     // (256+256)*32*2 bytes per K-tile buffer
#define ATILEB 16384    // A region size within buffer

__global__ __launch_bounds__(512, 2) void k_gemm256(
    const __bf16* __restrict__ A, const __bf16* __restrict__ B,
    const float* __restrict__ bias, float* __restrict__ C,
    int M, int N, int K)
{
    __shared__ __align__(16) char lds[4 * TILEB];   // 128 KiB
    const int tid = threadIdx.x;
    const int w = tid >> 6, lane = tid & 63;
    const int wm = w >> 2, wn = w & 3;              // 2 (M) x 4 (N) waves
    const int l31 = lane & 31, g = lane >> 5;
    const int NT = K / BKg;

    // bijective XCD-aware block swizzle (m204)
    const int nbx = N / 256;
    const int nwg = nbx * (M / 256);
    const int bid = (int)blockIdx.x;
    const int q = nwg >> 3, r = nwg & 7;
    const int xcd = bid & 7, loc = bid >> 3;
    const int swz = (xcd < r ? xcd * (q + 1) : r * (q + 1) + (xcd - r) * q) + loc;
    const int m0 = (swz / nbx) * 256;
    const int n0 = (swz % nbx) * 256;

    // staging source offsets (pre-swizzled global source, linear LDS dest)
    size_t aOff[2], bOff[2];
#pragma unroll
    for (int L = 0; L < 2; ++L) {
        int c = L * 512 + tid;
        int row = c >> 2, ch = (c & 3) ^ ((c >> 3) & 3);
        aOff[L] = (size_t)(m0 + row) * K + ch * 8;
        bOff[L] = (size_t)(n0 + row) * K + ch * 8;
    }
    int dstOff[2];
#pragma unroll
    for (int L = 0; L < 2; ++L) dstOff[L] = (L * 512 + w * 64) * 16;  // wave-uniform

    // fragment read offsets: row = l31 within 32-row tile, chunk kh*2+g,
    // swizzled by ((row>>1)&3) = ((l31>>1)&3)
    const int sw = (l31 >> 1) & 3;
    const int c0 = (g ^ sw) * 16;                        // kh=0 chunk byte
    const int aRd = (wm * 128 + l31) * 64 + c0;          // + mt*2048, ^32 for kh=1
    const int bRd = ATILEB + (wn * 64 + l31) * 64 + c0;  // + nt*2048, ^32 for kh=1

#define STAGE_A(tt, buf) do {                                              \
    const int kk_ = (tt) * BKg;                                            \
    gload16(A + aOff[0] + kk_, lds + (buf) * TILEB + dstOff[0]);           \
    gload16(A + aOff[1] + kk_, lds + (buf) * TILEB + dstOff[1]);           \
} while (0)
#define STAGE_B(tt, buf) do {                                              \
    const int kk_ = (tt) * BKg;                                            \
    gload16(B + bOff[0] + kk_, lds + (buf) * TILEB + ATILEB + dstOff[0]);  \
    gload16(B + bOff[1] + kk_, lds + (buf) * TILEB + ATILEB + dstOff[1]);  \
} while (0)
// XOR 32 only touches chunk bit (c0 in bits 4-5; row*64, mt*2048, buf*TILEB all higher)
#define RD_A(dst, buf, mt, kh) \
    dst = *(const bf16x8*)(lds + (buf) * TILEB + ((aRd + (mt) * 2048) ^ ((kh) * 32)))
#define RD_B(dst, buf, nt, kh) \
    dst = *(const bf16x8*)(lds + (buf) * TILEB + ((bRd + (nt) * 2048) ^ ((kh) * 32)))

    f32x16 acc[4][2] = {};
    bf16x8 a0[4], a1[4], bb0[2], bb1[2];

    // prologue: stage tiles 0,1,2 ; publish tile0 ; read kh=0 frags of tile0
    STAGE_A(0, 0); STAGE_B(0, 0);
    STAGE_A(1, 1); STAGE_B(1, 1);
    STAGE_A(2, 2); STAGE_B(2, 2);
    asm volatile("s_waitcnt vmcnt(8)" ::: "memory");
    __builtin_amdgcn_s_barrier();
    RD_A(a0[0], 0, 0, 0); RD_A(a0[1], 0, 1, 0); RD_A(a0[2], 0, 2, 0); RD_A(a0[3], 0, 3, 0);
    RD_B(bb0[0], 0, 0, 0); RD_B(bb0[1], 0, 1, 0);
    // steady-state invariant: 6 lgkm outstanding at each phase top

#define ITER(t) do {                                                        \
    const int bt = (t) & 3, bt1 = ((t) + 1) & 3, bt3 = ((t) + 3) & 3;       \
    int t3 = (t) + 3; if (t3 >= NT) t3 -= NT;                               \
    /* ---- tile boundary: ONE vmcnt + ONE barrier ---- */                  \
    asm volatile("s_waitcnt vmcnt(4)" ::: "memory");                        \
    __builtin_amdgcn_s_barrier();                                           \
    /* ---- ph0: stage A(t+3); read kh=1 frags of t; MFMA kh=0 ---- */      \
    STAGE_A(t3, bt3);                                                       \
    RD_A(a1[0], bt, 0, 1); RD_A(a1[1], bt, 1, 1);                           \
    RD_A(a1[2], bt, 2, 1); RD_A(a1[3], bt, 3, 1);                           \
    RD_B(bb1[0], bt, 0, 1); RD_B(bb1[1], bt, 1, 1);                         \
    asm volatile("s_waitcnt lgkmcnt(6)" ::: "memory");                      \
    __builtin_amdgcn_sched_barrier(0);                                      \
    __builtin_amdgcn_s_setprio(1);                                          \
    _Pragma("unroll")                                                       \
    for (int mt = 0; mt < 4; ++mt)                                          \
        _Pragma("unroll")                                                   \
        for (int nt = 0; nt < 2; ++nt)                                      \
            acc[mt][nt] = __builtin_amdgcn_mfma_f32_32x32x16_bf16(          \
                a0[mt], bb0[nt], acc[mt][nt], 0, 0, 0);                     \
    __builtin_amdgcn_s_setprio(0);                                          \
    __builtin_amdgcn_sched_barrier(0);                                      \
    /* ---- ph1: stage B(t+3); read kh=0 frags of t+1; MFMA kh=1 ---- */    \
    STAGE_B(t3, bt3);                                                       \
    if ((t) + 1 < NT) {                                                     \
        RD_A(a0[0], bt1, 0, 0); RD_A(a0[1], bt1, 1, 0);                     \
        RD_A(a0[2], bt1, 2, 0); RD_A(a0[3], bt1, 3, 0);                     \
        RD_B(bb0[0], bt1, 0, 0); RD_B(bb0[1], bt1, 1, 0);                   \
        asm volatile("s_waitcnt lgkmcnt(6)" ::: "memory");                  \
    } else {                                                                \
        asm volatile("s_waitcnt lgkmcnt(0)" ::: "memory");                  \
    }                                                                       \
    __builtin_amdgcn_sched_barrier(0);                                      \
    __builtin_amdgcn_s_setprio(1);                                          \
    _Pragma("unroll")                                                       \
    for (int mt = 0; mt < 4; ++mt)                                          \
        _Pragma("unroll")                                                   \
        for (int nt = 0; nt < 2; ++nt)                                      \
            acc[mt][nt] = __builtin_amdgcn_mfma_f32_32x32x16_bf16(          \
                a1[mt], bb1[nt], acc[mt][nt], 0, 0, 0);                     \
    __builtin_amdgcn_s_setprio(0);                                          \
    __builtin_amdgcn_sched_barrier(0);                                      \
} while (0)

    for (int t = 0; t < NT; t += 2) {
        ITER(t);
        ITER(t + 1);
    }

    // drain outstanding global_load_lds before block exit
    asm volatile("s_waitcnt vmcnt(0)" ::: "memory");

    // epilogue: C = acc + bias
    // 32x32 C/D layout: col = lane&31, row = (reg&3) + 8*(reg>>2) + 4*(lane>>5)
#pragma unroll
    for (int nt = 0; nt < 2; ++nt) {
        const int col = n0 + wn * 64 + nt * 32 + l31;
        const float bv = bias[col];
#pragma unroll
        for (int mt = 0; mt < 4; ++mt) {
#pragma unroll
            for (int qd = 0; qd < 4; ++qd) {
                const int rowb = m0 + wm * 128 + mt * 32 + qd * 8 + g * 4;
                const size_t base = (size_t)rowb * N + col;
                C[base]                 = acc[mt][nt][qd * 4 + 0] + bv;
                C[base + N]             = acc[mt][nt][qd * 4 + 1] + bv;
                C[base + 2 * (size_t)N] = acc[mt][nt][qd * 4 + 2] + bv;
                C[base + 3 * (size_t)N] = acc[mt][nt][qd * 4 + 3] + bv;
            }
        }
    }
#undef ITER
#undef STAGE_A
#undef STAGE_B
#undef RD_A
#undef RD_B
}

// ---- fallback 128x128 GEMM (round-1 verified) ----
template <int MODE>
__global__ __launch_bounds__(256, 2) void k_gemm(
    const __bf16* __restrict__ Ab, const float* __restrict__ Af,
    const __bf16* __restrict__ Bb, const int* __restrict__ Bq,
    const float* __restrict__ scale, const float* __restrict__ zp,
    const float* __restrict__ bias, float* __restrict__ C,
    int M, int N, int K, int NG, int GS)
{
    __shared__ __align__(16) __bf16 As[128 * 32];
    __shared__ __align__(16) __bf16 Bs[128 * 32];

    const int tid  = threadIdx.x;
    const int w    = tid >> 6;
    const int lane = tid & 63;
    const int wm   = w >> 1, wn = w & 1;
    const int m0   = blockIdx.y * 128, n0 = blockIdx.x * 128;
    const int lr   = lane & 15;
    const int lc   = lane >> 4;

    f32x4 acc[4][4] = {};

    for (int kk = 0; kk < K; kk += 32) {
        if constexpr (MODE == 0) {
#pragma unroll
            for (int i = 0; i < 2; i++) {
                int c = i * 256 + tid;
                const __bf16* g = Ab + (size_t)(m0 + (c >> 2)) * K + kk + (c & 3) * 8;
                gload16(g, (char*)As + (i * 256 + w * 64) * 16);
            }
        } else {
            int row = tid >> 1, half = tid & 1;
            const float* g = Af + (size_t)(m0 + row) * K + kk + half * 16;
            float4 f0 = *(const float4*)g;
            float4 f1 = *(const float4*)(g + 4);
            float4 f2 = *(const float4*)(g + 8);
            float4 f3 = *(const float4*)(g + 12);
            bf16x8 v0, v1;
            v0[0] = (__bf16)f0.x; v0[1] = (__bf16)f0.y; v0[2] = (__bf16)f0.z; v0[3] = (__bf16)f0.w;
            v0[4] = (__bf16)f1.x; v0[5] = (__bf16)f1.y; v0[6] = (__bf16)f1.z; v0[7] = (__bf16)f1.w;
            v1[0] = (__bf16)f2.x; v1[1] = (__bf16)f2.y; v1[2] = (__bf16)f2.z; v1[3] = (__bf16)f2.w;
            v1[4] = (__bf16)f3.x; v1[5] = (__bf16)f3.y; v1[6] = (__bf16)f3.z; v1[7] = (__bf16)f3.w;
            *(bf16x8*)(As + row * 32 + half * 16)     = v0;
            *(bf16x8*)(As + row * 32 + half * 16 + 8) = v1;
        }
        if constexpr (MODE <= 1) {
#pragma unroll
            for (int i = 0; i < 2; i++) {
                int c = i * 256 + tid;
                const __bf16* g = Bb + (size_t)(n0 + (c >> 2)) * K + kk + (c & 3) * 8;
                gload16(g, (char*)Bs + (i * 256 + w * 64) * 16);
            }
        } else {
            int row = tid >> 1, half = tid & 1;
            int o = n0 + row;
            int kbase = kk + half * 16;
            int g = kbase / GS;
            float s = scale[(size_t)o * NG + g];
            float z = zp[(size_t)o * NG + g];
            const int* qp = Bq + (size_t)o * K + kbase;
            int4 q0 = *(const int4*)qp;
            int4 q1 = *(const int4*)(qp + 4);
            int4 q2 = *(const int4*)(qp + 8);
            int4 q3 = *(const int4*)(qp + 12);
            bf16x8 v0, v1;
            v0[0] = (__bf16)(((float)q0.x - z) * s); v0[1] = (__bf16)(((float)q0.y - z) * s);
            v0[2] = (__bf16)(((float)q0.z - z) * s); v0[3] = (__bf16)(((float)q0.w - z) * s);
            v0[4] = (__bf16)(((float)q1.x - z) * s); v0[5] = (__bf16)(((float)q1.y - z) * s);
            v0[6] = (__bf16)(((float)q1.z - z) * s); v0[7] = (__bf16)(((float)q1.w - z) * s);
            v1[0] = (__bf16)(((float)q2.x - z) * s); v1[1] = (__bf16)(((float)q2.y - z) * s);
            v1[2] = (__bf16)(((float)q2.z - z) * s); v1[3] = (__bf16)(((float)q2.w - z) * s);
            v1[4] = (__bf16)(((float)q3.x - z) * s); v1[5] = (__bf16)(((float)q3.y - z) * s);
            v1[6] = (__bf16)(((float)q3.z - z) * s); v1[7] = (__bf16)(((float)q3.w - z) * s);
            *(bf16x8*)(Bs + row * 32 + half * 16)     = v0;
            *(bf16x8*)(Bs + row * 32 + half * 16 + 8) = v1;
        }

        __syncthreads();

        bf16x8 af[4], bfm[4];
#pragma unroll
        for (int a = 0; a < 4; a++)
            af[a] = *(const bf16x8*)(As + (wm * 64 + a * 16 + lr) * 32 + lc * 8);
#pragma unroll
        for (int b = 0; b < 4; b++)
            bfm[b] = *(const bf16x8*)(Bs + (wn * 64 + b * 16 + lr) * 32 + lc * 8);
#pragma unroll
        for (int a = 0; a < 4; a++)
#pragma unroll
            for (int b = 0; b < 4; b++)
                acc[a][b] = __builtin_amdgcn_mfma_f32_16x16x32_bf16(af[a], bfm[b], acc[a][b], 0, 0, 0);

        __syncthreads();
    }

#pragma unroll
    for (int b = 0; b < 4; b++) {
        int col = n0 + wn * 64 + b * 16 + lr;
        float bv = bias[col];
#pragma unroll
        for (int a = 0; a < 4; a++) {
            int rbase = m0 + wm * 64 + a * 16 + lc * 4;
#pragma unroll
            for (int r = 0; r < 4; r++)
                C[(size_t)(rbase + r) * N + col] = acc[a][b][r] + bv;
        }
    }
}

extern "C" void kernel_launch(void* const* d_in, const int* in_sizes, int n_in,
                              void* d_out, int out_size, void* d_ws, size_t ws_size,
                              hipStream_t stream) {
    const float* x     = (const float*)d_in[0];
    const int*   wq    = (const int*)d_in[1];
    const float* scale = (const float*)d_in[2];
    const float* zp    = (const float*)d_in[3];
    const float* bias  = (const float*)d_in[4];
    float* out = (float*)d_out;

    const int    N  = in_sizes[4];
    const long   K  = in_sizes[1] / N;
    const long   M  = in_sizes[0] / K;
    const int    NG = in_sizes[2] / N;
    const int    GS = (int)(K / NG);

    const size_t wbytes = (size_t)N * K * sizeof(__bf16);
    const size_t xbytes = (size_t)M * K * sizeof(__bf16);

    char* ws = (char*)d_ws;
    __bf16* wb = (__bf16*)ws;
    __bf16* xb = (__bf16*)(ws + wbytes);

    const bool big = (M % 256 == 0) && (N % 256 == 0) && (K % 64 == 0) && (K / 32 >= 4);

    if (ws_size >= wbytes + xbytes) {
        size_t nx = (size_t)M * K;
        size_t nw = (size_t)N * K;
        unsigned nxb = (unsigned)((nx / 8 + 255) / 256);
        unsigned nwb = (unsigned)((nw / 8 + 255) / 256);
        k_prep<<<nxb + nwb, 256, 0, stream>>>(x, xb, nx, wq, scale, zp, wb,
                                              (int)K, GS, NG, (int)nxb);
        if (big) {
            unsigned nwg = (unsigned)((M / 256) * (N / 256));
            k_gemm256<<<nwg, 512, 0, stream>>>(xb, wb, bias, out, (int)M, N, (int)K);
        } else {
            dim3 grid((unsigned)(N / 128), (unsigned)(M / 128)), blk(256);
            k_gemm<0><<<grid, blk, 0, stream>>>(xb, nullptr, wb, nullptr, scale, zp, bias, out,
                                                (int)M, N, (int)K, NG, GS);
        }
    } else if (ws_size >= wbytes) {
        size_t nw = (size_t)N * K;
        dim3 grid((unsigned)(N / 128), (unsigned)(M / 128)), blk(256);
        k_dequant_w<<<(unsigned)((nw / 8 + 255) / 256), 256, 0, stream>>>(wq, scale, zp, wb, (int)K, GS, NG);
        k_gemm<1><<<grid, blk, 0, stream>>>(nullptr, x, wb, nullptr, scale, zp, bias, out,
                                            (int)M, N, (int)K, NG, GS);
    } else {
        dim3 grid((unsigned)(N / 128), (unsigned)(M / 128)), blk(256);
        k_gemm<2><<<grid, blk, 0, stream>>>(nullptr, x, nullptr, wq, scale, zp, bias, out,
                                            (int)M, N, (int)K, NG, GS);
    }
}

// Round 12
// 144.315 us; speedup vs baseline: 1.1149x; 1.1149x over previous
//
#include <hip/hip_runtime.h>

typedef __bf16 bf16x8 __attribute__((ext_vector_type(8)));
typedef float f32x4 __attribute__((ext_vector_type(4)));

__device__ __forceinline__ void gload16(const void* g, void* l) {
    __builtin_amdgcn_global_load_lds(
        (const __attribute__((address_space(1))) unsigned int*)g,
        (__attribute__((address_space(3))) unsigned int*)l, 16, 0, 0);
}

// ---- fused pre-pass: x fp32->bf16 (blocks [0,nxb)), W dequant (blocks [nxb,...)) ----
__global__ void k_prep(const float* __restrict__ x, __bf16* __restrict__ xb, size_t nx,
                       const int* __restrict__ wq, const float* __restrict__ scale,
                       const float* __restrict__ zp, __bf16* __restrict__ wb,
                       int K, int GS, int NG, int nxb) {
    const int bid = (int)blockIdx.x;
    if (bid < nxb) {
        size_t i = ((size_t)bid * blockDim.x + threadIdx.x) * 8;
        if (i >= nx) return;
        const float4 a = *(const float4*)(x + i);
        const float4 b = *(const float4*)(x + i + 4);
        bf16x8 v;
        v[0] = (__bf16)a.x; v[1] = (__bf16)a.y; v[2] = (__bf16)a.z; v[3] = (__bf16)a.w;
        v[4] = (__bf16)b.x; v[5] = (__bf16)b.y; v[6] = (__bf16)b.z; v[7] = (__bf16)b.w;
        *(bf16x8*)(xb + i) = v;
    } else {
        size_t i = ((size_t)(bid - nxb) * blockDim.x + threadIdx.x) * 8;
        int o = (int)(i / K);
        int k = (int)(i % K);
        int g = k / GS;
        float s = scale[(size_t)o * NG + g];
        float z = zp[(size_t)o * NG + g];
        const int4 q0 = *(const int4*)(wq + i);
        const int4 q1 = *(const int4*)(wq + i + 4);
        bf16x8 v;
        v[0] = (__bf16)(((float)q0.x - z) * s); v[1] = (__bf16)(((float)q0.y - z) * s);
        v[2] = (__bf16)(((float)q0.z - z) * s); v[3] = (__bf16)(((float)q0.w - z) * s);
        v[4] = (__bf16)(((float)q1.x - z) * s); v[5] = (__bf16)(((float)q1.y - z) * s);
        v[6] = (__bf16)(((float)q1.z - z) * s); v[7] = (__bf16)(((float)q1.w - z) * s);
        *(bf16x8*)(wb + i) = v;
    }
}

// ---- standalone dequant (fallback MODE 1 path) ----
__global__ void k_dequant_w(const int* __restrict__ wq, const float* __restrict__ scale,
                            const float* __restrict__ zp, __bf16* __restrict__ wb,
                            int K, int GS, int NG) {
    size_t i = ((size_t)blockIdx.x * blockDim.x + threadIdx.x) * 8;
    int o = (int)(i / K);
    int k = (int)(i % K);
    int g = k / GS;
    float s = scale[(size_t)o * NG + g];
    float z = zp[(size_t)o * NG + g];
    const int4 q0 = *(const int4*)(wq + i);
    const int4 q1 = *(const int4*)(wq + i + 4);
    bf16x8 v;
    v[0] = (__bf16)(((float)q0.x - z) * s); v[1] = (__bf16)(((float)q0.y - z) * s);
    v[2] = (__bf16)(((float)q0.z - z) * s); v[3] = (__bf16)(((float)q0.w - z) * s);
    v[4] = (__bf16)(((float)q1.x - z) * s); v[5] = (__bf16)(((float)q1.y - z) * s);
    v[6] = (__bf16)(((float)q1.z - z) * s); v[7] = (__bf16)(((float)q1.w - z) * s);
    *(bf16x8*)(wb + i) = v;
}

// =====================================================================
// 256x256 deep-pipelined GEMM, BK=32, 4 LDS buffers, read-ahead frags,
// ONE barrier per K-tile.  ROUND-5 VERIFIED STRUCTURE — session optimum.
// (125.5us GEMM @ ~1100 TF, MfmaUtil 52%, bank conflicts 0, absmax 0.125.
//  Regressed variants: x4-unroll (r6: 265us, r7: 224us), 8-phase
//  double-barrier port (r9: 133us), 32x32x16 MFMA shape (r11: 140us,
//  bank conflicts 1.26e7 — 32-rows-per-half-wave fragment reads conflict
//  in a way the simple bank model does not predict; only the
//  16-rows x chunk-XOR-per-16-lane geometry is verified conflict-free).
//  Occupancy register-locked at 2 waves/SIMD (acc 128 + ~108 VGPR).)
// Hazard ledger:
//   vmcnt(4) @ tile-t top => all stages except tile t-1's 4 loads
//   complete; tile t+1's buffer (staged in t-2) published before its
//   first read (ph1 of tile t).
//   lgkm: 8 outstanding at tile top; lgkm(4) before m0-3 drains
//   a03(t)/B(t); lgkm(8) before m4-7 drains a47(t). Restage of buffer
//   (t-1)&3 (issued tile t) is separated from its last reads (completed
//   by lgkm(8) in tile t-1) by the tile-t barrier.
// Swizzle (T2): LDS[row][j] = G[row][j ^ ((row>>1)&3)], read chunk
// hi ^ ((lr>>1)&3) -> conflict-free ds_read_b128 (verified: conflicts=0).
// =====================================================================
#define BKg 32
#define TILEB 32768     // (256+256)*32*2 bytes per K-tile buffer
#define ATILEB 16384    // A region size within buffer

__global__ __launch_bounds__(512, 2) void k_gemm256(
    const __bf16* __restrict__ A, const __bf16* __restrict__ B,
    const float* __restrict__ bias, float* __restrict__ C,
    int M, int N, int K)
{
    __shared__ __align__(16) char lds[4 * TILEB];   // 128 KiB
    const int tid = threadIdx.x;
    const int w = tid >> 6, lane = tid & 63;
    const int wm = w >> 2, wn = w & 3;              // 2 (M) x 4 (N) waves
    const int lr = lane & 15, hi = lane >> 4;
    const int NT = K / BKg;

    // bijective XCD-aware block swizzle (m204)
    const int nbx = N / 256;
    const int nwg = nbx * (M / 256);
    const int bid = (int)blockIdx.x;
    const int q = nwg >> 3, r = nwg & 7;
    const int xcd = bid & 7, loc = bid >> 3;
    const int swz = (xcd < r ? xcd * (q + 1) : r * (q + 1) + (xcd - r) * q) + loc;
    const int m0 = (swz / nbx) * 256;
    const int n0 = (swz % nbx) * 256;

    // staging source offsets (pre-swizzled global source, linear LDS dest)
    size_t aOff[2], bOff[2];
#pragma unroll
    for (int L = 0; L < 2; ++L) {
        int c = L * 512 + tid;
        int row = c >> 2, ch = (c & 3) ^ ((c >> 3) & 3);
        aOff[L] = (size_t)(m0 + row) * K + ch * 8;
        bOff[L] = (size_t)(n0 + row) * K + ch * 8;
    }
    int dstOff[2];
#pragma unroll
    for (int L = 0; L < 2; ++L) dstOff[L] = (L * 512 + w * 64) * 16;  // wave-uniform

    // fragment read byte offsets (swizzled read: chunk = hi ^ ((row>>1)&3))
    const int chR = (hi ^ ((lr >> 1) & 3)) * 16;
    const int aRd = (wm * 128 + lr) * 64 + chR;
    const int bRd = ATILEB + (wn * 64 + lr) * 64 + chR;

#define STAGE_A(tt, buf) do {                                              \
    const int kk_ = (tt) * BKg;                                            \
    gload16(A + aOff[0] + kk_, lds + (buf) * TILEB + dstOff[0]);           \
    gload16(A + aOff[1] + kk_, lds + (buf) * TILEB + dstOff[1]);           \
} while (0)
#define STAGE_B(tt, buf) do {                                              \
    const int kk_ = (tt) * BKg;                                            \
    gload16(B + bOff[0] + kk_, lds + (buf) * TILEB + ATILEB + dstOff[0]);  \
    gload16(B + bOff[1] + kk_, lds + (buf) * TILEB + ATILEB + dstOff[1]);  \
} while (0)
#define RD_A(dst, buf, m) dst = *(const bf16x8*)(lds + (buf) * TILEB + aRd + (m) * 1024)
#define RD_B(dst, buf, n) dst = *(const bf16x8*)(lds + (buf) * TILEB + bRd + (n) * 1024)

    f32x4 acc[8][4] = {};
    bf16x8 a03[4], a47[4], b0[4], b1[4];

    // prologue: stage tiles 0,1,2 ; publish tile0 ; read ph0(0) frags
    STAGE_A(0, 0); STAGE_B(0, 0);
    STAGE_A(1, 1); STAGE_B(1, 1);
    STAGE_A(2, 2); STAGE_B(2, 2);
    asm volatile("s_waitcnt vmcnt(8)" ::: "memory");
    __builtin_amdgcn_s_barrier();
    RD_A(a03[0], 0, 0); RD_A(a03[1], 0, 1); RD_A(a03[2], 0, 2); RD_A(a03[3], 0, 3);
    RD_B(b0[0], 0, 0);  RD_B(b0[1], 0, 1);  RD_B(b0[2], 0, 2);  RD_B(b0[3], 0, 3);
    // steady-state invariant: 8 lgkm outstanding at each tile top

#define ITER(t, BCUR, BNXT) do {                                            \
    const int bt = (t) & 3, bt1 = ((t) + 1) & 3, bt3 = ((t) + 3) & 3;       \
    int t3 = (t) + 3; if (t3 >= NT) t3 -= NT;                               \
    /* ---- tile boundary: ONE vmcnt + ONE barrier ---- */                  \
    asm volatile("s_waitcnt vmcnt(4)" ::: "memory");                        \
    __builtin_amdgcn_s_barrier();                                           \
    /* ---- ph0: stage A(t+3); read a47(t); MFMA m0-3(t) ---- */            \
    STAGE_A(t3, bt3);                                                       \
    RD_A(a47[0], bt, 4); RD_A(a47[1], bt, 5);                               \
    RD_A(a47[2], bt, 6); RD_A(a47[3], bt, 7);                               \
    asm volatile("s_waitcnt lgkmcnt(4)" ::: "memory");                      \
    __builtin_amdgcn_sched_barrier(0);                                      \
    __builtin_amdgcn_s_setprio(1);                                          \
    _Pragma("unroll")                                                       \
    for (int m_ = 0; m_ < 4; ++m_)                                          \
        _Pragma("unroll")                                                   \
        for (int n_ = 0; n_ < 4; ++n_)                                      \
            acc[m_][n_] = __builtin_amdgcn_mfma_f32_16x16x32_bf16(          \
                a03[m_], BCUR[n_], acc[m_][n_], 0, 0, 0);                   \
    __builtin_amdgcn_s_setprio(0);                                          \
    __builtin_amdgcn_sched_barrier(0);                                      \
    /* ---- ph1: stage B(t+3); read a03/B(t+1); MFMA m4-7(t) ---- */        \
    STAGE_B(t3, bt3);                                                       \
    if ((t) + 1 < NT) {                                                     \
        RD_A(a03[0], bt1, 0); RD_A(a03[1], bt1, 1);                         \
        RD_A(a03[2], bt1, 2); RD_A(a03[3], bt1, 3);                         \
        RD_B(BNXT[0], bt1, 0); RD_B(BNXT[1], bt1, 1);                       \
        RD_B(BNXT[2], bt1, 2); RD_B(BNXT[3], bt1, 3);                       \
        asm volatile("s_waitcnt lgkmcnt(8)" ::: "memory");                  \
    } else {                                                                \
        asm volatile("s_waitcnt lgkmcnt(0)" ::: "memory");                  \
    }                                                                       \
    __builtin_amdgcn_sched_barrier(0);                                      \
    __builtin_amdgcn_s_setprio(1);                                          \
    _Pragma("unroll")                                                       \
    for (int m_ = 0; m_ < 4; ++m_)                                          \
        _Pragma("unroll")                                                   \
        for (int n_ = 0; n_ < 4; ++n_)                                      \
            acc[m_ + 4][n_] = __builtin_amdgcn_mfma_f32_16x16x32_bf16(      \
                a47[m_], BCUR[n_], acc[m_ + 4][n_], 0, 0, 0);               \
    __builtin_amdgcn_s_setprio(0);                                          \
    __builtin_amdgcn_sched_barrier(0);                                      \
} while (0)

    for (int t = 0; t < NT; t += 2) {
        ITER(t,     b0, b1);
        ITER(t + 1, b1, b0);
    }

    // drain outstanding global_load_lds before block exit
    asm volatile("s_waitcnt vmcnt(0)" ::: "memory");

    // epilogue: C = acc + bias (C/D layout: col=lane&15, row=(lane>>4)*4+reg)
#pragma unroll
    for (int n_ = 0; n_ < 4; ++n_) {
        const int col = n0 + wn * 64 + n_ * 16 + lr;
        const float bv = bias[col];
#pragma unroll
        for (int m_ = 0; m_ < 8; ++m_) {
            const size_t rbase = (size_t)(m0 + wm * 128 + m_ * 16 + hi * 4) * N + col;
            C[rbase]                 = acc[m_][n_][0] + bv;
            C[rbase + N]             = acc[m_][n_][1] + bv;
            C[rbase + 2 * (size_t)N] = acc[m_][n_][2] + bv;
            C[rbase + 3 * (size_t)N] = acc[m_][n_][3] + bv;
        }
    }
#undef ITER
#undef STAGE_A
#undef STAGE_B
#undef RD_A
#undef RD_B
}

// ---- fallback 128x128 GEMM (round-1 verified) ----
template <int MODE>
__global__ __launch_bounds__(256, 2) void k_gemm(
    const __bf16* __restrict__ Ab, const float* __restrict__ Af,
    const __bf16* __restrict__ Bb, const int* __restrict__ Bq,
    const float* __restrict__ scale, const float* __restrict__ zp,
    const float* __restrict__ bias, float* __restrict__ C,
    int M, int N, int K, int NG, int GS)
{
    __shared__ __align__(16) __bf16 As[128 * 32];
    __shared__ __align__(16) __bf16 Bs[128 * 32];

    const int tid  = threadIdx.x;
    const int w    = tid >> 6;
    const int lane = tid & 63;
    const int wm   = w >> 1, wn = w & 1;
    const int m0   = blockIdx.y * 128, n0 = blockIdx.x * 128;
    const int lr   = lane & 15;
    const int lc   = lane >> 4;

    f32x4 acc[4][4] = {};

    for (int kk = 0; kk < K; kk += 32) {
        if constexpr (MODE == 0) {
#pragma unroll
            for (int i = 0; i < 2; i++) {
                int c = i * 256 + tid;
                const __bf16* g = Ab + (size_t)(m0 + (c >> 2)) * K + kk + (c & 3) * 8;
                gload16(g, (char*)As + (i * 256 + w * 64) * 16);
            }
        } else {
            int row = tid >> 1, half = tid & 1;
            const float* g = Af + (size_t)(m0 + row) * K + kk + half * 16;
            float4 f0 = *(const float4*)g;
            float4 f1 = *(const float4*)(g + 4);
            float4 f2 = *(const float4*)(g + 8);
            float4 f3 = *(const float4*)(g + 12);
            bf16x8 v0, v1;
            v0[0] = (__bf16)f0.x; v0[1] = (__bf16)f0.y; v0[2] = (__bf16)f0.z; v0[3] = (__bf16)f0.w;
            v0[4] = (__bf16)f1.x; v0[5] = (__bf16)f1.y; v0[6] = (__bf16)f1.z; v0[7] = (__bf16)f1.w;
            v1[0] = (__bf16)f2.x; v1[1] = (__bf16)f2.y; v1[2] = (__bf16)f2.z; v1[3] = (__bf16)f2.w;
            v1[4] = (__bf16)f3.x; v1[5] = (__bf16)f3.y; v1[6] = (__bf16)f3.z; v1[7] = (__bf16)f3.w;
            *(bf16x8*)(As + row * 32 + half * 16)     = v0;
            *(bf16x8*)(As + row * 32 + half * 16 + 8) = v1;
        }
        if constexpr (MODE <= 1) {
#pragma unroll
            for (int i = 0; i < 2; i++) {
                int c = i * 256 + tid;
                const __bf16* g = Bb + (size_t)(n0 + (c >> 2)) * K + kk + (c & 3) * 8;
                gload16(g, (char*)Bs + (i * 256 + w * 64) * 16);
            }
        } else {
            int row = tid >> 1, half = tid & 1;
            int o = n0 + row;
            int kbase = kk + half * 16;
            int g = kbase / GS;
            float s = scale[(size_t)o * NG + g];
            float z = zp[(size_t)o * NG + g];
            const int* qp = Bq + (size_t)o * K + kbase;
            int4 q0 = *(const int4*)qp;
            int4 q1 = *(const int4*)(qp + 4);
            int4 q2 = *(const int4*)(qp + 8);
            int4 q3 = *(const int4*)(qp + 12);
            bf16x8 v0, v1;
            v0[0] = (__bf16)(((float)q0.x - z) * s); v0[1] = (__bf16)(((float)q0.y - z) * s);
            v0[2] = (__bf16)(((float)q0.z - z) * s); v0[3] = (__bf16)(((float)q0.w - z) * s);
            v0[4] = (__bf16)(((float)q1.x - z) * s); v0[5] = (__bf16)(((float)q1.y - z) * s);
            v0[6] = (__bf16)(((float)q1.z - z) * s); v0[7] = (__bf16)(((float)q1.w - z) * s);
            v1[0] = (__bf16)(((float)q2.x - z) * s); v1[1] = (__bf16)(((float)q2.y - z) * s);
            v1[2] = (__bf16)(((float)q2.z - z) * s); v1[3] = (__bf16)(((float)q2.w - z) * s);
            v1[4] = (__bf16)(((float)q3.x - z) * s); v1[5] = (__bf16)(((float)q3.y - z) * s);
            v1[6] = (__bf16)(((float)q3.z - z) * s); v1[7] = (__bf16)(((float)q3.w - z) * s);
            *(bf16x8*)(Bs + row * 32 + half * 16)     = v0;
            *(bf16x8*)(Bs + row * 32 + half * 16 + 8) = v1;
        }

        __syncthreads();

        bf16x8 af[4], bfm[4];
#pragma unroll
        for (int a = 0; a < 4; a++)
            af[a] = *(const bf16x8*)(As + (wm * 64 + a * 16 + lr) * 32 + lc * 8);
#pragma unroll
        for (int b = 0; b < 4; b++)
            bfm[b] = *(const bf16x8*)(Bs + (wn * 64 + b * 16 + lr) * 32 + lc * 8);
#pragma unroll
        for (int a = 0; a < 4; a++)
#pragma unroll
            for (int b = 0; b < 4; b++)
                acc[a][b] = __builtin_amdgcn_mfma_f32_16x16x32_bf16(af[a], bfm[b], acc[a][b], 0, 0, 0);

        __syncthreads();
    }

#pragma unroll
    for (int b = 0; b < 4; b++) {
        int col = n0 + wn * 64 + b * 16 + lr;
        float bv = bias[col];
#pragma unroll
        for (int a = 0; a < 4; a++) {
            int rbase = m0 + wm * 64 + a * 16 + lc * 4;
#pragma unroll
            for (int r = 0; r < 4; r++)
                C[(size_t)(rbase + r) * N + col] = acc[a][b][r] + bv;
        }
    }
}

extern "C" void kernel_launch(void* const* d_in, const int* in_sizes, int n_in,
                              void* d_out, int out_size, void* d_ws, size_t ws_size,
                              hipStream_t stream) {
    const float* x     = (const float*)d_in[0];
    const int*   wq    = (const int*)d_in[1];
    const float* scale = (const float*)d_in[2];
    const float* zp    = (const float*)d_in[3];
    const float* bias  = (const float*)d_in[4];
    float* out = (float*)d_out;

    const int    N  = in_sizes[4];
    const long   K  = in_sizes[1] / N;
    const long   M  = in_sizes[0] / K;
    const int    NG = in_sizes[2] / N;
    const int    GS = (int)(K / NG);

    const size_t wbytes = (size_t)N * K * sizeof(__bf16);
    const size_t xbytes = (size_t)M * K * sizeof(__bf16);

    char* ws = (char*)d_ws;
    __bf16* wb = (__bf16*)ws;
    __bf16* xb = (__bf16*)(ws + wbytes);

    const bool big = (M % 256 == 0) && (N % 256 == 0) && (K % 64 == 0) && (K / 32 >= 4);

    if (ws_size >= wbytes + xbytes) {
        size_t nx = (size_t)M * K;
        size_t nw = (size_t)N * K;
        unsigned nxb = (unsigned)((nx / 8 + 255) / 256);
        unsigned nwb = (unsigned)((nw / 8 + 255) / 256);
        k_prep<<<nxb + nwb, 256, 0, stream>>>(x, xb, nx, wq, scale, zp, wb,
                                              (int)K, GS, NG, (int)nxb);
        if (big) {
            unsigned nwg = (unsigned)((M / 256) * (N / 256));
            k_gemm256<<<nwg, 512, 0, stream>>>(xb, wb, bias, out, (int)M, N, (int)K);
        } else {
            dim3 grid((unsigned)(N / 128), (unsigned)(M / 128)), blk(256);
            k_gemm<0><<<grid, blk, 0, stream>>>(xb, nullptr, wb, nullptr, scale, zp, bias, out,
                                                (int)M, N, (int)K, NG, GS);
        }
    } else if (ws_size >= wbytes) {
        size_t nw = (size_t)N * K;
        dim3 grid((unsigned)(N / 128), (unsigned)(M / 128)), blk(256);
        k_dequant_w<<<(unsigned)((nw / 8 + 255) / 256), 256, 0, stream>>>(wq, scale, zp, wb, (int)K, GS, NG);
        k_gemm<1><<<grid, blk, 0, stream>>>(nullptr, x, wb, nullptr, scale, zp, bias, out,
                                            (int)M, N, (int)K, NG, GS);
    } else {
        dim3 grid((unsigned)(N / 128), (unsigned)(M / 128)), blk(256);
        k_gemm<2><<<grid, blk, 0, stream>>>(nullptr, x, nullptr, wq, scale, zp, bias, out,
                                            (int)M, N, (int)K, NG, GS);
    }
}